// Round 4
// baseline (730.353 us; speedup 1.0000x reference)
//
#include <hip/hip_runtime.h>
#include <hip/hip_bf16.h>
#include <math.h>

#define D 2048
#define H_ 16
#define HD 128
#define L_ 2
#define V_ 32000
#define BS_ 16
#define B_ 16
#define MAXCTX 1024
#define NBLK 64
#define FF 8192
#define SPLITS 8
#define CHUNK 128

// ---------------- embed: x[b,:] = wte[ids[b],:] ----------------
__global__ void embed_kernel(const int* __restrict__ ids,
                             const float* __restrict__ wte,
                             float* __restrict__ x) {
  int i = blockIdx.x * 256 + threadIdx.x;      // 0..32767
  int b = i >> 11, d = i & 2047;
  x[i] = wte[(size_t)ids[b] * D + d];
}

// ---------------- layernorm (no affine) + optional zeroing of a scratch buf ----------------
__global__ void ln_kernel(const float* __restrict__ X,
                          float* __restrict__ T,
                          float* __restrict__ Z, int zfloats) {
  if (blockIdx.x >= B_) {
    int nb = gridDim.x - B_;
    int idx = (blockIdx.x - B_) * 256 + threadIdx.x;
    int n4 = zfloats >> 2;
    float4* z4 = (float4*)Z;
    for (int i = idx; i < n4; i += nb * 256) z4[i] = make_float4(0.f, 0.f, 0.f, 0.f);
    return;
  }
  __shared__ float xs[D];
  __shared__ float red[8];
  int b = blockIdx.x, tid = threadIdx.x;
  int wid = tid >> 6, lane = tid & 63;
  float s = 0.f;
  for (int i = tid; i < D; i += 256) { float v = X[(size_t)b * D + i]; xs[i] = v; s += v; }
#pragma unroll
  for (int m = 32; m; m >>= 1) s += __shfl_xor(s, m);
  if (lane == 0) red[wid] = s;
  __syncthreads();
  float mu = (red[0] + red[1] + red[2] + red[3]) * (1.f / D);
  float vs = 0.f;
  for (int i = tid; i < D; i += 256) { float dd = xs[i] - mu; vs += dd * dd; }
#pragma unroll
  for (int m = 32; m; m >>= 1) vs += __shfl_xor(vs, m);
  if (lane == 0) red[4 + wid] = vs;
  __syncthreads();
  float var = (red[4] + red[5] + red[6] + red[7]) * (1.f / D);
  float r = 1.f / sqrtf(var + 1e-5f);
  for (int i = tid; i < D; i += 256) T[(size_t)b * D + i] = (xs[i] - mu) * r;
}

// ---------------- gemm: O(16,N) += T(16,K) @ W(K,N), split-K, atomic accumulate ----------------
__global__ void gemm_acc_kernel(const float* __restrict__ T,
                                const float* __restrict__ W,
                                float* __restrict__ O,
                                int K, int N) {
  __shared__ __align__(16) float tl[64][20];
  int tid = threadIdx.x;
  int j = blockIdx.x * 256 + tid;
  int k0 = blockIdx.y * 64;
#pragma unroll
  for (int r = 0; r < 4; r++) {
    int ii = tid + r * 256;
    int b = ii >> 6, k = ii & 63;
    tl[k][b] = T[(size_t)b * K + k0 + k];
  }
  __syncthreads();
  float acc[16];
#pragma unroll
  for (int b = 0; b < 16; b++) acc[b] = 0.f;
  const float* wp = W + (size_t)k0 * N + j;
#pragma unroll 4
  for (int k = 0; k < 64; k++) {
    float w = wp[(size_t)k * N];
    const float4* tr = (const float4*)(&tl[k][0]);
    float4 t0 = tr[0], t1 = tr[1], t2 = tr[2], t3 = tr[3];
    acc[0]  += t0.x * w; acc[1]  += t0.y * w; acc[2]  += t0.z * w; acc[3]  += t0.w * w;
    acc[4]  += t1.x * w; acc[5]  += t1.y * w; acc[6]  += t1.z * w; acc[7]  += t1.w * w;
    acc[8]  += t2.x * w; acc[9]  += t2.y * w; acc[10] += t2.z * w; acc[11] += t2.w * w;
    acc[12] += t3.x * w; acc[13] += t3.y * w; acc[14] += t3.z * w; acc[15] += t3.w * w;
  }
#pragma unroll
  for (int b = 0; b < 16; b++) atomicAdd(&O[(size_t)b * N + j], acc[b]);
}

// ---------------- attention split (flash-decoding): block per (b,h,split) ----------------
__global__ void attn_split_kernel(const float* __restrict__ Q,    // (16, 2048)
                                  const float* __restrict__ KVn,  // (16, 256)
                                  const float* __restrict__ KC,
                                  const float* __restrict__ VC,
                                  const int* __restrict__ BT,     // (16, 64)
                                  const int* __restrict__ CL,
                                  float* __restrict__ Pout,       // (256, 8, 128)
                                  float* __restrict__ Pms) {      // (256, 8, 2)
  int bh = blockIdx.x, sp = blockIdx.y;
  int b = bh >> 4, h = bh & 15;
  int ctx = CL[b];
  int s0 = sp * CHUNK;
  if (s0 >= ctx) return;
  int s1 = min(s0 + CHUNK, ctx);
  int n = s1 - s0;
  int last = ctx - 1;
  int tid = threadIdx.x, wid = tid >> 6, lane = tid & 63;
  __shared__ float sc[CHUNK];
  __shared__ int btl[8];
  __shared__ float2 red[4][64];
  __shared__ float stat[8];
  if (tid < 8) btl[tid] = BT[b * NBLK + sp * 8 + tid];
  __syncthreads();
  float slope = exp2f(-0.5f * (float)(h + 1));
  const float scl = 0.08838834764831845f;   // 1/sqrt(128)
  float2 q2 = ((const float2*)(Q + (size_t)b * D + h * HD))[lane];

  // phase 1: scores (wave per position)
  for (int s = s0 + wid; s < s1; s += 4) {
    const float* kp;
    if (s == last) kp = KVn + b * 256;
    else {
      int blk = btl[(s - s0) >> 4];
      kp = KC + ((size_t)blk * BS_ + (s & 15)) * (H_ * HD) + h * HD;
    }
    float2 k2 = ((const float2*)kp)[lane];
    float p = q2.x * k2.x + q2.y * k2.y;
#pragma unroll
    for (int m = 32; m; m >>= 1) p += __shfl_xor(p, m);
    if (lane == 0) sc[s - s0] = p * scl + slope * (float)(s - last);
  }
  __syncthreads();

  // phase 2: local softmax stats (unnormalized)
  float mx = -1e30f;
  for (int i = tid; i < n; i += 256) mx = fmaxf(mx, sc[i]);
#pragma unroll
  for (int m = 32; m; m >>= 1) mx = fmaxf(mx, __shfl_xor(mx, m));
  if (lane == 0) stat[wid] = mx;
  __syncthreads();
  mx = fmaxf(fmaxf(stat[0], stat[1]), fmaxf(stat[2], stat[3]));
  float sum = 0.f;
  for (int i = tid; i < n; i += 256) { float e = expf(sc[i] - mx); sc[i] = e; sum += e; }
#pragma unroll
  for (int m = 32; m; m >>= 1) sum += __shfl_xor(sum, m);
  if (lane == 0) stat[4 + wid] = sum;
  __syncthreads();

  // phase 3: PV partial (unnormalized)
  float2 a0 = make_float2(0.f, 0.f), a1 = make_float2(0.f, 0.f);
  int s = s0 + wid;
  for (; s + 4 < s1; s += 8) {
    {
      const float* vp = (s == last) ? KVn + b * 256 + HD
                                    : VC + ((size_t)btl[(s - s0) >> 4] * BS_ + (s & 15)) * (H_ * HD) + h * HD;
      float2 v2 = ((const float2*)vp)[lane];
      float p = sc[s - s0];
      a0.x += p * v2.x; a0.y += p * v2.y;
    }
    {
      int t1i = s + 4;
      const float* vp = (t1i == last) ? KVn + b * 256 + HD
                                      : VC + ((size_t)btl[(t1i - s0) >> 4] * BS_ + (t1i & 15)) * (H_ * HD) + h * HD;
      float2 v2 = ((const float2*)vp)[lane];
      float p = sc[t1i - s0];
      a1.x += p * v2.x; a1.y += p * v2.y;
    }
  }
  for (; s < s1; s += 4) {
    const float* vp = (s == last) ? KVn + b * 256 + HD
                                  : VC + ((size_t)btl[(s - s0) >> 4] * BS_ + (s & 15)) * (H_ * HD) + h * HD;
    float2 v2 = ((const float2*)vp)[lane];
    float p = sc[s - s0];
    a0.x += p * v2.x; a0.y += p * v2.y;
  }
  a0.x += a1.x; a0.y += a1.y;
  red[wid][lane] = a0;
  __syncthreads();
  if (tid < 64) {
    float2 r0 = red[0][tid], r1 = red[1][tid], r2 = red[2][tid], r3 = red[3][tid];
    float2 o;
    o.x = r0.x + r1.x + r2.x + r3.x;
    o.y = r0.y + r1.y + r2.y + r3.y;
    ((float2*)(Pout + ((size_t)(bh * SPLITS + sp) << 7)))[tid] = o;
  }
  if (tid == 0) {
    Pms[(bh * SPLITS + sp) * 2 + 0] = mx;
    Pms[(bh * SPLITS + sp) * 2 + 1] = stat[4] + stat[5] + stat[6] + stat[7];
  }
}

// ---------------- attention combine: block per (b,h), 128 threads ----------------
__global__ void attn_combine_kernel(const float* __restrict__ Pout,
                                    const float* __restrict__ Pms,
                                    const int* __restrict__ CL,
                                    float* __restrict__ O) {
  int bh = blockIdx.x;
  int b = bh >> 4, h = bh & 15;
  int ctx = CL[b];
  int nsp = (ctx + CHUNK - 1) >> 7;
  int d = threadIdx.x;
  float M = -1e30f;
#pragma unroll 2
  for (int i = 0; i < nsp; i++) M = fmaxf(M, Pms[(bh * SPLITS + i) * 2]);
  float total = 0.f, o = 0.f;
#pragma unroll 2
  for (int i = 0; i < nsp; i++) {
    float mi = Pms[(bh * SPLITS + i) * 2];
    float si = Pms[(bh * SPLITS + i) * 2 + 1];
    float w = expf(mi - M);
    total += si * w;
    o += w * Pout[((size_t)(bh * SPLITS + i) << 7) + d];
  }
  O[(size_t)b * D + h * HD + d] = o / total;
}

// ---------------- swiglu ----------------
__global__ void swiglu_kernel(const float* __restrict__ Hb, float* __restrict__ U) {
  int i = blockIdx.x * 256 + threadIdx.x;    // 0..65535
  int b = i >> 12, c = i & 4095;
  float a = Hb[(size_t)b * FF + c];
  float g = Hb[(size_t)b * FF + 4096 + c];
  U[i] = a * (g / (1.f + expf(-g)));
}

// ---------------- logits: out(16,V) = T(16,2048) @ wte(V,2048)^T ----------------
// block = 256 (4 waves), wave owns 4 vocab rows; T read from global (L2-resident);
// per-block 16x16 output tile staged in LDS, stored coalesced (64B per b-row).
__global__ void logits_kernel(const float* __restrict__ T,
                              const float* __restrict__ wte,
                              float* __restrict__ O) {
  __shared__ float sums[4][16][4];
  int tid = threadIdx.x;
  int wid = tid >> 6, lane = tid & 63;
  int vbase = blockIdx.x * 16 + wid * 4;
  float acc[16][4];
#pragma unroll
  for (int b = 0; b < 16; b++)
#pragma unroll
    for (int vi = 0; vi < 4; vi++) acc[b][vi] = 0.f;

  const float* wp = wte + (size_t)vbase * D;
#pragma unroll 4
  for (int it = 0; it < 32; it++) {
    int dg = it * 64 + lane;
    float w0 = wp[dg];
    float w1 = wp[D + dg];
    float w2 = wp[2 * D + dg];
    float w3 = wp[3 * D + dg];
#pragma unroll
    for (int b = 0; b < 16; b++) {
      float tv = T[b * D + dg];
      acc[b][0] += tv * w0;
      acc[b][1] += tv * w1;
      acc[b][2] += tv * w2;
      acc[b][3] += tv * w3;
    }
  }
  // reduce each accumulator to lane 0, stage in LDS (static indices only)
#pragma unroll
  for (int b = 0; b < 16; b++)
#pragma unroll
    for (int vi = 0; vi < 4; vi++) {
      float v = acc[b][vi];
#pragma unroll
      for (int m = 32; m; m >>= 1) v += __shfl_xor(v, m);
      if (lane == 0) sums[wid][b][vi] = v;
    }
  __syncthreads();
  // coalesced store of the 16x16 tile: thread t -> (b = t>>4, v = t&15)
  int b = tid >> 4, v = tid & 15;
  O[(size_t)b * V_ + blockIdx.x * 16 + v] = sums[v >> 2][b][v & 3];
}

extern "C" void kernel_launch(void* const* d_in, const int* in_sizes, int n_in,
                              void* d_out, int out_size, void* d_ws, size_t ws_size,
                              hipStream_t stream) {
  const int* ids   = (const int*)d_in[0];
  const int* bt    = (const int*)d_in[2];
  const int* cl    = (const int*)d_in[3];
  const float* wte = (const float*)d_in[5];
  const float* Wq  = (const float*)d_in[6];
  const float* Wkv = (const float*)d_in[7];
  const float* Wo  = (const float*)d_in[8];
  const float* Wff1= (const float*)d_in[9];
  const float* Wff2= (const float*)d_in[10];
  const float* KC  = (const float*)d_in[11];
  const float* VC  = (const float*)d_in[12];
  float* out = (float*)d_out;
  float* ws  = (float*)d_ws;

  // workspace layout (floats)
  float* x    = ws;             // 16*2048
  float* t    = ws + 32768;     // 16*2048
  float* q    = ws + 65536;     // 16*2048
  float* kv   = ws + 98304;     // 16*256
  float* ao   = ws + 102400;    // 16*2048
  float* hb   = ws + 135168;    // 16*8192
  float* u    = ws + 266240;    // 16*4096
  float* pout = ws + 331776;    // 256*8*128 = 262144
  float* pms  = ws + 593920;    // 256*8*2  = 4096

  embed_kernel<<<128, 256, 0, stream>>>(ids, wte, x);
  for (int l = 0; l < L_; l++) {
    ln_kernel<<<16 + 64, 256, 0, stream>>>(x, t, q, 32768 + 4096);
    gemm_acc_kernel<<<dim3(8, 32), 256, 0, stream>>>(t, Wq + (size_t)l * 4194304, q, 2048, 2048);
    gemm_acc_kernel<<<dim3(1, 32), 256, 0, stream>>>(t, Wkv + (size_t)l * 524288, kv, 2048, 256);
    attn_split_kernel<<<dim3(256, SPLITS), 256, 0, stream>>>(q, kv,
                                         KC + (size_t)l * 33554432,
                                         VC + (size_t)l * 33554432,
                                         bt, cl, pout, pms);
    attn_combine_kernel<<<256, 128, 0, stream>>>(pout, pms, cl, ao);
    gemm_acc_kernel<<<dim3(8, 32), 256, 0, stream>>>(ao, Wo + (size_t)l * 4194304, x, 2048, 2048);
    ln_kernel<<<16 + 128, 256, 0, stream>>>(x, t, hb, 131072);
    gemm_acc_kernel<<<dim3(32, 32), 256, 0, stream>>>(t, Wff1 + (size_t)l * 16777216, hb, 2048, 8192);
    swiglu_kernel<<<256, 256, 0, stream>>>(hb, u);
    gemm_acc_kernel<<<dim3(8, 64), 256, 0, stream>>>(u, Wff2 + (size_t)l * 8388608, x, 4096, 2048);
  }
  ln_kernel<<<16, 256, 0, stream>>>(x, t, (float*)nullptr, 0);
  logits_kernel<<<2000, 256, 0, stream>>>(t, wte, out);
}

// Round 5
// 387.140 us; speedup vs baseline: 1.8865x; 1.8865x over previous
//
#include <hip/hip_runtime.h>
#include <hip/hip_bf16.h>
#include <math.h>

#define D 2048
#define H_ 16
#define HD 128
#define L_ 2
#define V_ 32000
#define BS_ 16
#define B_ 16
#define MAXCTX 1024
#define NBLK 64
#define FF 8192
#define SPLITS 8
#define CHUNK 128

// ---------------- embed: x[b,:] = wte[ids[b],:] ----------------
__global__ void embed_kernel(const int* __restrict__ ids,
                             const float* __restrict__ wte,
                             float* __restrict__ x) {
  int i = blockIdx.x * 256 + threadIdx.x;      // 0..32767
  int b = i >> 11, d = i & 2047;
  x[i] = wte[(size_t)ids[b] * D + d];
}

// ---------------- layernorm (no affine) + optional zeroing of a scratch buf ----------------
__global__ void ln_kernel(const float* __restrict__ X,
                          float* __restrict__ T,
                          float* __restrict__ Z, int zfloats) {
  if (blockIdx.x >= B_) {
    int nb = gridDim.x - B_;
    int idx = (blockIdx.x - B_) * 256 + threadIdx.x;
    int n4 = zfloats >> 2;
    float4* z4 = (float4*)Z;
    for (int i = idx; i < n4; i += nb * 256) z4[i] = make_float4(0.f, 0.f, 0.f, 0.f);
    return;
  }
  __shared__ float xs[D];
  __shared__ float red[8];
  int b = blockIdx.x, tid = threadIdx.x;
  int wid = tid >> 6, lane = tid & 63;
  float s = 0.f;
  for (int i = tid; i < D; i += 256) { float v = X[(size_t)b * D + i]; xs[i] = v; s += v; }
#pragma unroll
  for (int m = 32; m; m >>= 1) s += __shfl_xor(s, m);
  if (lane == 0) red[wid] = s;
  __syncthreads();
  float mu = (red[0] + red[1] + red[2] + red[3]) * (1.f / D);
  float vs = 0.f;
  for (int i = tid; i < D; i += 256) { float dd = xs[i] - mu; vs += dd * dd; }
#pragma unroll
  for (int m = 32; m; m >>= 1) vs += __shfl_xor(vs, m);
  if (lane == 0) red[4 + wid] = vs;
  __syncthreads();
  float var = (red[4] + red[5] + red[6] + red[7]) * (1.f / D);
  float r = 1.f / sqrtf(var + 1e-5f);
  for (int i = tid; i < D; i += 256) T[(size_t)b * D + i] = (xs[i] - mu) * r;
}

// ---------------- gemm: O(16,N) += T(16,K) @ W(K,N), split-K, atomic accumulate ----------------
__global__ void gemm_acc_kernel(const float* __restrict__ T,
                                const float* __restrict__ W,
                                float* __restrict__ O,
                                int K, int N) {
  __shared__ __align__(16) float tl[64][20];
  int tid = threadIdx.x;
  int j = blockIdx.x * 256 + tid;
  int k0 = blockIdx.y * 64;
#pragma unroll
  for (int r = 0; r < 4; r++) {
    int ii = tid + r * 256;
    int b = ii >> 6, k = ii & 63;
    tl[k][b] = T[(size_t)b * K + k0 + k];
  }
  __syncthreads();
  float acc[16];
#pragma unroll
  for (int b = 0; b < 16; b++) acc[b] = 0.f;
  const float* wp = W + (size_t)k0 * N + j;
#pragma unroll 4
  for (int k = 0; k < 64; k++) {
    float w = wp[(size_t)k * N];
    const float4* tr = (const float4*)(&tl[k][0]);
    float4 t0 = tr[0], t1 = tr[1], t2 = tr[2], t3 = tr[3];
    acc[0]  += t0.x * w; acc[1]  += t0.y * w; acc[2]  += t0.z * w; acc[3]  += t0.w * w;
    acc[4]  += t1.x * w; acc[5]  += t1.y * w; acc[6]  += t1.z * w; acc[7]  += t1.w * w;
    acc[8]  += t2.x * w; acc[9]  += t2.y * w; acc[10] += t2.z * w; acc[11] += t2.w * w;
    acc[12] += t3.x * w; acc[13] += t3.y * w; acc[14] += t3.z * w; acc[15] += t3.w * w;
  }
#pragma unroll
  for (int b = 0; b < 16; b++) atomicAdd(&O[(size_t)b * N + j], acc[b]);
}

// ---------------- attention split (flash-decoding): block per (b,h,split) ----------------
__global__ void attn_split_kernel(const float* __restrict__ Q,    // (16, 2048)
                                  const float* __restrict__ KVn,  // (16, 256)
                                  const float* __restrict__ KC,
                                  const float* __restrict__ VC,
                                  const int* __restrict__ BT,     // (16, 64)
                                  const int* __restrict__ CL,
                                  float* __restrict__ Pout,       // (256, 8, 128)
                                  float* __restrict__ Pms) {      // (256, 8, 2)
  int bh = blockIdx.x, sp = blockIdx.y;
  int b = bh >> 4, h = bh & 15;
  int ctx = CL[b];
  int s0 = sp * CHUNK;
  if (s0 >= ctx) return;
  int s1 = min(s0 + CHUNK, ctx);
  int n = s1 - s0;
  int last = ctx - 1;
  int tid = threadIdx.x, wid = tid >> 6, lane = tid & 63;
  __shared__ float sc[CHUNK];
  __shared__ int btl[8];
  __shared__ float2 red[4][64];
  __shared__ float stat[8];
  if (tid < 8) btl[tid] = BT[b * NBLK + sp * 8 + tid];
  __syncthreads();
  float slope = exp2f(-0.5f * (float)(h + 1));
  const float scl = 0.08838834764831845f;   // 1/sqrt(128)
  float2 q2 = ((const float2*)(Q + (size_t)b * D + h * HD))[lane];

  // phase 1: scores (wave per position)
  for (int s = s0 + wid; s < s1; s += 4) {
    const float* kp;
    if (s == last) kp = KVn + b * 256;
    else {
      int blk = btl[(s - s0) >> 4];
      kp = KC + ((size_t)blk * BS_ + (s & 15)) * (H_ * HD) + h * HD;
    }
    float2 k2 = ((const float2*)kp)[lane];
    float p = q2.x * k2.x + q2.y * k2.y;
#pragma unroll
    for (int m = 32; m; m >>= 1) p += __shfl_xor(p, m);
    if (lane == 0) sc[s - s0] = p * scl + slope * (float)(s - last);
  }
  __syncthreads();

  // phase 2: local softmax stats (unnormalized)
  float mx = -1e30f;
  for (int i = tid; i < n; i += 256) mx = fmaxf(mx, sc[i]);
#pragma unroll
  for (int m = 32; m; m >>= 1) mx = fmaxf(mx, __shfl_xor(mx, m));
  if (lane == 0) stat[wid] = mx;
  __syncthreads();
  mx = fmaxf(fmaxf(stat[0], stat[1]), fmaxf(stat[2], stat[3]));
  float sum = 0.f;
  for (int i = tid; i < n; i += 256) { float e = expf(sc[i] - mx); sc[i] = e; sum += e; }
#pragma unroll
  for (int m = 32; m; m >>= 1) sum += __shfl_xor(sum, m);
  if (lane == 0) stat[4 + wid] = sum;
  __syncthreads();

  // phase 3: PV partial (unnormalized)
  float2 a0 = make_float2(0.f, 0.f), a1 = make_float2(0.f, 0.f);
  int s = s0 + wid;
  for (; s + 4 < s1; s += 8) {
    {
      const float* vp = (s == last) ? KVn + b * 256 + HD
                                    : VC + ((size_t)btl[(s - s0) >> 4] * BS_ + (s & 15)) * (H_ * HD) + h * HD;
      float2 v2 = ((const float2*)vp)[lane];
      float p = sc[s - s0];
      a0.x += p * v2.x; a0.y += p * v2.y;
    }
    {
      int t1i = s + 4;
      const float* vp = (t1i == last) ? KVn + b * 256 + HD
                                      : VC + ((size_t)btl[(t1i - s0) >> 4] * BS_ + (t1i & 15)) * (H_ * HD) + h * HD;
      float2 v2 = ((const float2*)vp)[lane];
      float p = sc[t1i - s0];
      a1.x += p * v2.x; a1.y += p * v2.y;
    }
  }
  for (; s < s1; s += 4) {
    const float* vp = (s == last) ? KVn + b * 256 + HD
                                  : VC + ((size_t)btl[(s - s0) >> 4] * BS_ + (s & 15)) * (H_ * HD) + h * HD;
    float2 v2 = ((const float2*)vp)[lane];
    float p = sc[s - s0];
    a0.x += p * v2.x; a0.y += p * v2.y;
  }
  a0.x += a1.x; a0.y += a1.y;
  red[wid][lane] = a0;
  __syncthreads();
  if (tid < 64) {
    float2 r0 = red[0][tid], r1 = red[1][tid], r2 = red[2][tid], r3 = red[3][tid];
    float2 o;
    o.x = r0.x + r1.x + r2.x + r3.x;
    o.y = r0.y + r1.y + r2.y + r3.y;
    ((float2*)(Pout + ((size_t)(bh * SPLITS + sp) << 7)))[tid] = o;
  }
  if (tid == 0) {
    Pms[(bh * SPLITS + sp) * 2 + 0] = mx;
    Pms[(bh * SPLITS + sp) * 2 + 1] = stat[4] + stat[5] + stat[6] + stat[7];
  }
}

// ---------------- attention combine: block per (b,h), 128 threads ----------------
__global__ void attn_combine_kernel(const float* __restrict__ Pout,
                                    const float* __restrict__ Pms,
                                    const int* __restrict__ CL,
                                    float* __restrict__ O) {
  int bh = blockIdx.x;
  int b = bh >> 4, h = bh & 15;
  int ctx = CL[b];
  int nsp = (ctx + CHUNK - 1) >> 7;
  int d = threadIdx.x;
  float M = -1e30f;
#pragma unroll 2
  for (int i = 0; i < nsp; i++) M = fmaxf(M, Pms[(bh * SPLITS + i) * 2]);
  float total = 0.f, o = 0.f;
#pragma unroll 2
  for (int i = 0; i < nsp; i++) {
    float mi = Pms[(bh * SPLITS + i) * 2];
    float si = Pms[(bh * SPLITS + i) * 2 + 1];
    float w = expf(mi - M);
    total += si * w;
    o += w * Pout[((size_t)(bh * SPLITS + i) << 7) + d];
  }
  O[(size_t)b * D + h * HD + d] = o / total;
}

// ---------------- swiglu ----------------
__global__ void swiglu_kernel(const float* __restrict__ Hb, float* __restrict__ U) {
  int i = blockIdx.x * 256 + threadIdx.x;    // 0..65535
  int b = i >> 12, c = i & 4095;
  float a = Hb[(size_t)b * FF + c];
  float g = Hb[(size_t)b * FF + 4096 + c];
  U[i] = a * (g / (1.f + expf(-g)));
}

// ---------------- logits: out(16,V) = T(16,2048) @ wte(V,2048)^T ----------------
// block = 256 (4 waves), wave owns 4 vocab rows, all loads float4.
// acc[64] kept in VGPRs (launch_bounds lifts the default 64-reg cap that caused
// scratch spills = the 745MB WRITE_SIZE in the previous round).
// Final reduce: multi-value butterfly, 63 shfl total; lane l ends with the sum
// for flat index l (b = l>>2, vi = l&3) -> direct coalesced 16x16 tile store.
__global__ __launch_bounds__(256, 2)
void logits_kernel(const float* __restrict__ T,
                   const float* __restrict__ wte,
                   float* __restrict__ O) {
  int tid = threadIdx.x;
  int wid = tid >> 6, lane = tid & 63;
  int vbase = blockIdx.x * 16 + wid * 4;
  const float4* T4 = (const float4*)T;            // 16 rows x 512 float4
  const float4* W4 = (const float4*)(wte + (size_t)vbase * D);
  float acc[64];                                   // flat index = b*4 + vi
#pragma unroll
  for (int j = 0; j < 64; j++) acc[j] = 0.f;

#pragma unroll 2
  for (int it = 0; it < 8; it++) {
    int idx = it * 64 + lane;                      // float4 index within row
    float4 w0 = W4[idx];
    float4 w1 = W4[512 + idx];
    float4 w2 = W4[1024 + idx];
    float4 w3 = W4[1536 + idx];
#pragma unroll
    for (int b = 0; b < 16; b++) {
      float4 t4 = T4[b * 512 + idx];
      acc[b * 4 + 0] += t4.x * w0.x + t4.y * w0.y + t4.z * w0.z + t4.w * w0.w;
      acc[b * 4 + 1] += t4.x * w1.x + t4.y * w1.y + t4.z * w1.z + t4.w * w1.w;
      acc[b * 4 + 2] += t4.x * w2.x + t4.y * w2.y + t4.z * w2.z + t4.w * w2.w;
      acc[b * 4 + 3] += t4.x * w3.x + t4.y * w3.y + t4.z * w3.z + t4.w * w3.w;
    }
  }

  // multi-value butterfly reduce: 64 independent lane-sums in 63 shfls.
  // After step m, live value i has original index 2*i*? -- invariant: vals[i]
  // holds partial sum for original index i*2^(st+1) + (lane & (2^(st+1)-1)).
#pragma unroll
  for (int st = 0; st < 6; st++) {
    const int m = 1 << st;
    const int n = 64 >> (st + 1);
    const bool hi = (lane & m) != 0;
#pragma unroll
    for (int i = 0; i < n; i++) {
      float a = acc[2 * i], b = acc[2 * i + 1];
      float send = hi ? a : b;
      float keep = hi ? b : a;
      acc[i] = keep + __shfl_xor(send, m);
    }
  }
  // lane l holds total for b = l>>2, vi = l&3
  O[(size_t)(lane >> 2) * V_ + vbase + (lane & 3)] = acc[0];
}

extern "C" void kernel_launch(void* const* d_in, const int* in_sizes, int n_in,
                              void* d_out, int out_size, void* d_ws, size_t ws_size,
                              hipStream_t stream) {
  const int* ids   = (const int*)d_in[0];
  const int* bt    = (const int*)d_in[2];
  const int* cl    = (const int*)d_in[3];
  const float* wte = (const float*)d_in[5];
  const float* Wq  = (const float*)d_in[6];
  const float* Wkv = (const float*)d_in[7];
  const float* Wo  = (const float*)d_in[8];
  const float* Wff1= (const float*)d_in[9];
  const float* Wff2= (const float*)d_in[10];
  const float* KC  = (const float*)d_in[11];
  const float* VC  = (const float*)d_in[12];
  float* out = (float*)d_out;
  float* ws  = (float*)d_ws;

  // workspace layout (floats)
  float* x    = ws;             // 16*2048
  float* t    = ws + 32768;     // 16*2048
  float* q    = ws + 65536;     // 16*2048
  float* kv   = ws + 98304;     // 16*256
  float* ao   = ws + 102400;    // 16*2048
  float* hb   = ws + 135168;    // 16*8192
  float* u    = ws + 266240;    // 16*4096
  float* pout = ws + 331776;    // 256*8*128 = 262144
  float* pms  = ws + 593920;    // 256*8*2  = 4096

  embed_kernel<<<128, 256, 0, stream>>>(ids, wte, x);
  for (int l = 0; l < L_; l++) {
    ln_kernel<<<16 + 64, 256, 0, stream>>>(x, t, q, 32768 + 4096);
    gemm_acc_kernel<<<dim3(8, 32), 256, 0, stream>>>(t, Wq + (size_t)l * 4194304, q, 2048, 2048);
    gemm_acc_kernel<<<dim3(1, 32), 256, 0, stream>>>(t, Wkv + (size_t)l * 524288, kv, 2048, 256);
    attn_split_kernel<<<dim3(256, SPLITS), 256, 0, stream>>>(q, kv,
                                         KC + (size_t)l * 33554432,
                                         VC + (size_t)l * 33554432,
                                         bt, cl, pout, pms);
    attn_combine_kernel<<<256, 128, 0, stream>>>(pout, pms, cl, ao);
    gemm_acc_kernel<<<dim3(8, 32), 256, 0, stream>>>(ao, Wo + (size_t)l * 4194304, x, 2048, 2048);
    ln_kernel<<<16 + 128, 256, 0, stream>>>(x, t, hb, 131072);
    gemm_acc_kernel<<<dim3(32, 32), 256, 0, stream>>>(t, Wff1 + (size_t)l * 16777216, hb, 2048, 8192);
    swiglu_kernel<<<256, 256, 0, stream>>>(hb, u);
    gemm_acc_kernel<<<dim3(8, 64), 256, 0, stream>>>(u, Wff2 + (size_t)l * 8388608, x, 4096, 2048);
  }
  ln_kernel<<<16, 256, 0, stream>>>(x, t, (float*)nullptr, 0);
  logits_kernel<<<2000, 256, 0, stream>>>(t, wte, out);
}